// Round 3
// baseline (180.188 us; speedup 1.0000x reference)
//
#include <hip/hip_runtime.h>

#define IMG_W 1024
#define IMG_H 1024
#define ROWS  4          // output rows per block tile

typedef float v4f __attribute__((ext_vector_type(4)));

__global__ __launch_bounds__(256) void dir_rhs_kernel(
    const float* __restrict__ u,
    const float* __restrict__ f,
    const float* __restrict__ wt,
    float* __restrict__ out)
{
    // 16 images * 256 tiles = 4096 blocks. XCD-chunked bijective swizzle
    // (4096 % 8 == 0): each XCD gets 512 consecutive tiles -> adjacent tiles
    // (which share u halo rows) live on the same XCD's L2.
    const int orig = blockIdx.x;
    const int tile = (orig & 7) * 512 + (orig >> 3);

    const int b    = tile >> 8;              // 256 tiles per image
    const int r0   = (tile & 255) << 2;      // first output row of tile
    const int tid  = threadIdx.x;            // 0..255
    const int lane = tid & 63;
    const int j0   = tid << 2;               // 4 columns per thread
    const size_t img = (size_t)b << 20;

    const float* ub = u   + img;
    const float* fb = f   + img;
    float*       ob = out + img;

    const bool le = (j0 == 0);               // covers col 0  (boundary in v)
    const bool re = (j0 == IMG_W - 4);       // covers col 1023

    // Broadcast weight loads (L1-cached)
    const float w00 = wt[0], w01 = wt[1], w02 = wt[2];
    const float w10 = wt[3], w11 = wt[4], w12 = wt[5];
    const float w20 = wt[6], w21 = wt[7], w22 = wt[8];
    const float cof = (float)(-(1.0 / 1023.0) * (1.0 / 1023.0) / 4.0);

    // ---- Phase 1: issue ALL vector loads up front (single latency exposure,
    //      10 outstanding dwordx4 per thread) ----
    v4f ur[ROWS + 2];                        // u rows r0-1 .. r0+4
    #pragma unroll
    for (int k = 0; k < ROWS + 2; k++) {
        const int r = r0 - 1 + k;
        const bool valid = (r >= 1) && (r <= IMG_H - 2);   // block-uniform
        if (valid) {
            ur[k] = *(const v4f*)(ub + (size_t)r * IMG_W + j0);
        } else {
            ur[k] = (v4f){0.f, 0.f, 0.f, 0.f};             // row is boundary in v
        }
    }
    v4f fr[ROWS];
    #pragma unroll
    for (int k = 0; k < ROWS; k++) {
        const int r = r0 + k;
        if (r >= 1 && r <= IMG_H - 2) {
            fr[k] = *(const v4f*)(fb + (size_t)r * IMG_W + j0);
        } else {
            fr[k] = (v4f){0.f, 0.f, 0.f, 0.f};
        }
    }

    // ---- Phase 2: halo columns via intra-wave shuffle; only the cross-wave
    //      lane (lane 0 / lane 63) falls back to a 1-lane predicated load,
    //      which is an L1 hit (same line as the neighbor's vector load). ----
    float lft[ROWS + 2], rgt[ROWS + 2];
    #pragma unroll
    for (int k = 0; k < ROWS + 2; k++) {
        const int r = r0 - 1 + k;
        const bool valid = (r >= 1) && (r <= IMG_H - 2);
        float l  = __shfl_up(ur[k].w, 1);     // col j0-1 from lane-1
        float rr = __shfl_down(ur[k].x, 1);   // col j0+4 from lane+1
        if (valid && lane == 0  && !le) l  = ub[(size_t)r * IMG_W + j0 - 1];
        if (valid && lane == 63 && !re) rr = ub[(size_t)r * IMG_W + j0 + 4];
        lft[k] = (le || !valid) ? 0.f : l;
        rgt[k] = (re || !valid) ? 0.f : rr;
    }

    // Boundary columns of v are zero (after shuffles so neighbors got true u)
    if (le) {
        #pragma unroll
        for (int k = 0; k < ROWS + 2; k++) ur[k].x = 0.f;   // col 0
    }
    if (re) {
        #pragma unroll
        for (int k = 0; k < ROWS + 2; k++) ur[k].w = 0.f;   // col 1023
    }

    // ---- Phase 3: compute + nontemporal store ----
    #pragma unroll
    for (int k = 0; k < ROWS; k++) {
        const int r = r0 + k;
        v4f* o4 = (v4f*)(ob + (size_t)r * IMG_W + j0);

        if (r == 0 || r == IMG_H - 1) {
            v4f z = {0.f, 0.f, 0.f, 0.f};
            __builtin_nontemporal_store(z, o4);
        } else {
            const v4f n = ur[k], c = ur[k + 1], s = ur[k + 2];
            float res0 = cof * fr[k].x
                       + w00 * lft[k]     + w01 * n.x + w02 * n.y
                       + w10 * lft[k + 1] + w11 * c.x + w12 * c.y
                       + w20 * lft[k + 2] + w21 * s.x + w22 * s.y;
            float res1 = cof * fr[k].y
                       + w00 * n.x + w01 * n.y + w02 * n.z
                       + w10 * c.x + w11 * c.y + w12 * c.z
                       + w20 * s.x + w21 * s.y + w22 * s.z;
            float res2 = cof * fr[k].z
                       + w00 * n.y + w01 * n.z + w02 * n.w
                       + w10 * c.y + w11 * c.z + w12 * c.w
                       + w20 * s.y + w21 * s.z + w22 * s.w;
            float res3 = cof * fr[k].w
                       + w00 * n.z + w01 * n.w + w02 * rgt[k]
                       + w10 * c.z + w11 * c.w + w12 * rgt[k + 1]
                       + w20 * s.z + w21 * s.w + w22 * rgt[k + 2];
            if (le) res0 = 0.f;              // col 0 stays Dirichlet
            if (re) res3 = 0.f;              // col 1023 stays Dirichlet
            v4f rv = {res0, res1, res2, res3};
            __builtin_nontemporal_store(rv, o4);
        }
    }
}

extern "C" void kernel_launch(void* const* d_in, const int* in_sizes, int n_in,
                              void* d_out, int out_size, void* d_ws, size_t ws_size,
                              hipStream_t stream) {
    const float* u  = (const float*)d_in[0];
    const float* f  = (const float*)d_in[1];
    const float* wt = (const float*)d_in[2];
    float* out = (float*)d_out;

    const int B = 16;
    dim3 grid(B * (IMG_H / ROWS));   // 4096 blocks
    dim3 block(256);                 // 256 threads * 4 cols = 1024-wide tile
    dir_rhs_kernel<<<grid, block, 0, stream>>>(u, f, wt, out);
}

// Round 4
// 172.948 us; speedup vs baseline: 1.0419x; 1.0419x over previous
//
#include <hip/hip_runtime.h>

#define IMG_W 1024
#define IMG_H 1024

typedef float v4f __attribute__((ext_vector_type(4)));

__global__ __launch_bounds__(256) void dir_rhs_kernel(
    const float* __restrict__ u,
    const float* __restrict__ f,
    const float* __restrict__ wt,
    float* __restrict__ out)
{
    const int row = blockIdx.x;            // b*1024 + i
    const int b   = row >> 10;
    const int i   = row & (IMG_H - 1);
    const int tid = threadIdx.x;           // 0..255
    const int j0  = tid << 2;              // 4 columns per thread
    const size_t img = (size_t)b << 20;

    const float* ub = u + img;

    // Clamped row addresses: every load below is unconditionally in-bounds.
    const int rn = (i >= 1) ? i - 1 : 0;
    const int rs = (i <= IMG_H - 2) ? i + 1 : IMG_H - 1;
    const float* pn = ub + (size_t)rn * IMG_W;
    const float* pc = ub + (size_t)i  * IMG_W;
    const float* ps = ub + (size_t)rs * IMG_W;

    const bool le = (j0 == 0);             // thread covering col 0
    const bool re = (j0 == IMG_W - 4);     // thread covering col 1023
    const int  jl = le ? 0 : j0 - 1;       // clamped halo columns
    const int  jr = re ? IMG_W - 1 : j0 + 4;

    // ---- ALL loads issued straight-line: 4x dwordx4 + 6 scalars, one batch ----
    v4f n4 = *(const v4f*)(pn + j0);
    v4f c4 = *(const v4f*)(pc + j0);
    v4f s4 = *(const v4f*)(ps + j0);
    v4f f4 = *(const v4f*)(f + img + (size_t)i * IMG_W + j0);
    float nl = pn[jl], nr = pn[jr];
    float cl = pc[jl], cr = pc[jr];
    float sl = ps[jl], sr = ps[jr];

    // Block-uniform validity masks, folded into the weights (SALU-side).
    const float sN = (i >= 2)         ? 1.f : 0.f;   // row i-1 interior in v
    const float sS = (i <= IMG_H - 3) ? 1.f : 0.f;   // row i+1 interior in v
    const float keep = (i >= 1 && i <= IMG_H - 2) ? 1.f : 0.f;  // output row interior

    const float w00 = wt[0] * sN, w01 = wt[1] * sN, w02 = wt[2] * sN;
    const float w10 = wt[3],      w11 = wt[4],      w12 = wt[5];
    const float w20 = wt[6] * sS, w21 = wt[7] * sS, w22 = wt[8] * sS;
    const float cof = keep * (float)(-(1.0 / 1023.0) * (1.0 / 1023.0) / 4.0);

    // Boundary columns of v are Dirichlet-zero (lane-level selects).
    if (le) { nl = cl = sl = 0.f; n4.x = c4.x = s4.x = 0.f; }
    if (re) { nr = cr = sr = 0.f; n4.w = c4.w = s4.w = 0.f; }

    float res0 = cof * f4.x
               + w00 * nl  + w01 * n4.x + w02 * n4.y
               + w10 * cl  + w11 * c4.x + w12 * c4.y
               + w20 * sl  + w21 * s4.x + w22 * s4.y;
    float res1 = cof * f4.y
               + w00 * n4.x + w01 * n4.y + w02 * n4.z
               + w10 * c4.x + w11 * c4.y + w12 * c4.z
               + w20 * s4.x + w21 * s4.y + w22 * s4.z;
    float res2 = cof * f4.z
               + w00 * n4.y + w01 * n4.z + w02 * n4.w
               + w10 * c4.y + w11 * c4.z + w12 * c4.w
               + w20 * s4.y + w21 * s4.z + w22 * s4.w;
    float res3 = cof * f4.w
               + w00 * n4.z + w01 * n4.w + w02 * nr
               + w10 * c4.z + w11 * c4.w + w12 * cr
               + w20 * s4.z + w21 * s4.w + w22 * sr;

    // Dirichlet output rows/cols -> exactly zero (keep is block-uniform).
    res0 *= keep; res1 *= keep; res2 *= keep; res3 *= keep;
    if (le) res0 = 0.f;
    if (re) res3 = 0.f;

    v4f rv = {res0, res1, res2, res3};
    __builtin_nontemporal_store(rv, (v4f*)(out + img + (size_t)i * IMG_W + j0));
}

extern "C" void kernel_launch(void* const* d_in, const int* in_sizes, int n_in,
                              void* d_out, int out_size, void* d_ws, size_t ws_size,
                              hipStream_t stream) {
    const float* u  = (const float*)d_in[0];
    const float* f  = (const float*)d_in[1];
    const float* wt = (const float*)d_in[2];
    float* out = (float*)d_out;

    const int B = 16;
    dim3 grid(B * IMG_H);   // one block per (batch, row): 16384 blocks = 64/CU
    dim3 block(256);        // 256 threads * 4 cols = 1024-wide row
    dir_rhs_kernel<<<grid, block, 0, stream>>>(u, f, wt, out);
}

// Round 6
// 167.339 us; speedup vs baseline: 1.0768x; 1.0335x over previous
//
#include <hip/hip_runtime.h>

#define IMG_W 1024
#define IMG_H 1024

typedef float v4f __attribute__((ext_vector_type(4)));

__global__ __launch_bounds__(256) void dir_rhs_kernel(
    const float* __restrict__ u,
    const float* __restrict__ f,
    const float* __restrict__ wt,
    float* __restrict__ out)
{
    const int row = blockIdx.x;            // b*1024 + i
    const int b   = row >> 10;
    const int i   = row & (IMG_H - 1);
    const int tid = threadIdx.x;           // 0..255
    const int j0  = tid << 2;              // 4 columns per thread
    const size_t img = (size_t)b << 20;

    const float* ub = u + img;

    // Clamped row addresses: every load below is unconditionally in-bounds.
    const int rn = (i >= 1) ? i - 1 : 0;
    const int rs = (i <= IMG_H - 2) ? i + 1 : IMG_H - 1;
    const float* pn = ub + (size_t)rn * IMG_W;
    const float* pc = ub + (size_t)i  * IMG_W;
    const float* ps = ub + (size_t)rs * IMG_W;

    const bool le = (j0 == 0);             // thread covering col 0
    const bool re = (j0 == IMG_W - 4);     // thread covering col 1023

    // Clamped, 16B-aligned halo vector addresses (coalesced across the wave:
    // lane stride is exactly 16B for each of these).
    const int jm = le ? 0          : j0 - 4;   // left halo vector [j0-4 .. j0-1]
    const int jp = re ? IMG_W - 4  : j0 + 4;   // right halo vector [j0+4 .. j0+7]

    // ---- ALL loads issued straight-line: 10x dwordx4, every one coalesced ----
    v4f n4 = *(const v4f*)(pn + j0);
    v4f c4 = *(const v4f*)(pc + j0);
    v4f s4 = *(const v4f*)(ps + j0);
    v4f nm = *(const v4f*)(pn + jm);
    v4f cm = *(const v4f*)(pc + jm);
    v4f sm = *(const v4f*)(ps + jm);
    v4f np = *(const v4f*)(pn + jp);
    v4f cp = *(const v4f*)(pc + jp);
    v4f sp = *(const v4f*)(ps + jp);
    v4f f4 = *(const v4f*)(f + img + (size_t)i * IMG_W + j0);

    // Halo scalars from the vector loads' edge lanes.
    float nl = nm.w, cl = cm.w, sl = sm.w;
    float nr = np.x, cr = cp.x, sr = sp.x;

    // Block-uniform validity masks, folded into the weights (SALU-side).
    const float sN = (i >= 2)         ? 1.f : 0.f;   // row i-1 interior in v
    const float sS = (i <= IMG_H - 3) ? 1.f : 0.f;   // row i+1 interior in v
    const float keep = (i >= 1 && i <= IMG_H - 2) ? 1.f : 0.f;  // output row interior

    const float w00 = wt[0] * sN, w01 = wt[1] * sN, w02 = wt[2] * sN;
    const float w10 = wt[3],      w11 = wt[4],      w12 = wt[5];
    const float w20 = wt[6] * sS, w21 = wt[7] * sS, w22 = wt[8] * sS;
    const float cof = keep * (float)(-(1.0 / 1023.0) * (1.0 / 1023.0) / 4.0);

    // Boundary columns of v are Dirichlet-zero (lane-level selects).
    if (le) { nl = cl = sl = 0.f; n4.x = c4.x = s4.x = 0.f; }
    if (re) { nr = cr = sr = 0.f; n4.w = c4.w = s4.w = 0.f; }

    float res0 = cof * f4.x
               + w00 * nl  + w01 * n4.x + w02 * n4.y
               + w10 * cl  + w11 * c4.x + w12 * c4.y
               + w20 * sl  + w21 * s4.x + w22 * s4.y;
    float res1 = cof * f4.y
               + w00 * n4.x + w01 * n4.y + w02 * n4.z
               + w10 * c4.x + w11 * c4.y + w12 * c4.z
               + w20 * s4.x + w21 * s4.y + w22 * s4.z;
    float res2 = cof * f4.z
               + w00 * n4.y + w01 * n4.z + w02 * n4.w
               + w10 * c4.y + w11 * c4.z + w12 * c4.w
               + w20 * s4.y + w21 * s4.z + w22 * s4.w;
    float res3 = cof * f4.w
               + w00 * n4.z + w01 * n4.w + w02 * nr
               + w10 * c4.z + w11 * c4.w + w12 * cr
               + w20 * s4.z + w21 * s4.w + w22 * sr;

    // Dirichlet output rows/cols -> exactly zero (keep is block-uniform).
    res0 *= keep; res1 *= keep; res2 *= keep; res3 *= keep;
    if (le) res0 = 0.f;
    if (re) res3 = 0.f;

    v4f rv = {res0, res1, res2, res3};
    __builtin_nontemporal_store(rv, (v4f*)(out + img + (size_t)i * IMG_W + j0));
}

extern "C" void kernel_launch(void* const* d_in, const int* in_sizes, int n_in,
                              void* d_out, int out_size, void* d_ws, size_t ws_size,
                              hipStream_t stream) {
    const float* u  = (const float*)d_in[0];
    const float* f  = (const float*)d_in[1];
    const float* wt = (const float*)d_in[2];
    float* out = (float*)d_out;

    const int B = 16;
    dim3 grid(B * IMG_H);   // one block per (batch, row): 16384 blocks = 64/CU
    dim3 block(256);        // 256 threads * 4 cols = 1024-wide row
    dir_rhs_kernel<<<grid, block, 0, stream>>>(u, f, wt, out);
}